// Round 4
// baseline (71.861 us; speedup 1.0000x reference)
//
#include <hip/hip_runtime.h>
#include <math.h>

#define BT 32
#define OT 32
#define IT 128
#define NTHREADS 256
#define IN_F 256
#define OUT_F 256

// out[b,o] = (1 + min_i((x-1)*pe)) * n0 + (-1 + max_i((x-1)*pe + 2*pe)) * n1
// pe = sigmoid(w0 - w1), n0 = sigmoid(pw0 - pw1), n1 = 1 - n0.
__global__ __launch_bounds__(NTHREADS, 2)
void den_kernel(const float* __restrict__ x,
                const float* __restrict__ pew,
                const float* __restrict__ pnw,
                float* __restrict__ out, int B)
{
    // x-1 transposed [i][b], +1 pad => conflict-free ds_read_b32 (bank = (i+tb)%32)
    __shared__ __align__(16) float x_lds[IT][BT + 1];
    // pe transposed [i][o], +4 pad => row stride 144B keeps float4 reads 16B-aligned
    __shared__ __align__(16) float pe_lds[IT][OT + 4];

    const int tid = threadIdx.x;
    const int tb  = tid & 31;    // b within tile (1 per thread)
    const int to  = tid >> 5;    // o-group (0..7), 4 consecutive o per thread
    const int b0  = blockIdx.x * BT;
    const int o0  = blockIdx.y * OT;

    const int srow = tid >> 3;   // staging row 0..31
    const int sc   = tid & 7;    // staging col group 0..7

    float accmin0 = INFINITY,  accmin1 = INFINITY,  accmin2 = INFINITY,  accmin3 = INFINITY;
    float accmax0 = -INFINITY, accmax1 = -INFINITY, accmax2 = -INFINITY, accmax3 = -INFINITY;

    for (int it = 0; it < IN_F; it += IT) {
        if (it) __syncthreads();   // protect LDS before overwrite

        // ---- stage x tile: 32 rows x 128 i, as (x-1) transposed ----
        const float4* xg = reinterpret_cast<const float4*>(x + (size_t)(b0 + srow) * IN_F + it);
        #pragma unroll
        for (int k = 0; k < 4; ++k) {
            float4 g = xg[sc + 8 * k];
            int il = (sc + 8 * k) * 4;
            x_lds[il + 0][srow] = g.x - 1.0f;
            x_lds[il + 1][srow] = g.y - 1.0f;
            x_lds[il + 2][srow] = g.z - 1.0f;
            x_lds[il + 3][srow] = g.w - 1.0f;
        }

        // ---- stage pe tile: 32 o-rows x 128 i; fused 2-way softmax ----
        const float4* wg = reinterpret_cast<const float4*>(pew + ((size_t)(o0 + srow) * IN_F + it) * 2);
        #pragma unroll
        for (int k = 0; k < 8; ++k) {
            float4 w = wg[sc + 8 * k];              // (w0_i, w1_i, w0_{i+1}, w1_{i+1})
            int il = (sc + 8 * k) * 2;
            float e0 = __expf(w.y - w.x);
            float e1 = __expf(w.w - w.z);
            pe_lds[il + 0][srow] = __builtin_amdgcn_rcpf(1.0f + e0);
            pe_lds[il + 1][srow] = __builtin_amdgcn_rcpf(1.0f + e1);
        }
        __syncthreads();

        // ---- main VALU loop: per 2 i-steps: 2 ds_read_b32 + 2 ds_read_b128, 24 VALU ----
        #pragma unroll 4
        for (int i = 0; i < IT; i += 2) {
            float xm0 = x_lds[i + 0][tb];
            float xm1 = x_lds[i + 1][tb];
            float4 p0 = *reinterpret_cast<const float4*>(&pe_lds[i + 0][to * 4]);
            float4 p1 = *reinterpret_cast<const float4*>(&pe_lds[i + 1][to * 4]);

            { float t0 = xm0 * p0.x, t1 = xm1 * p1.x;
              float u0 = __builtin_fmaf(2.0f, p0.x, t0), u1 = __builtin_fmaf(2.0f, p1.x, t1);
              accmin0 = fminf(fminf(accmin0, t0), t1);
              accmax0 = fmaxf(fmaxf(accmax0, u0), u1); }
            { float t0 = xm0 * p0.y, t1 = xm1 * p1.y;
              float u0 = __builtin_fmaf(2.0f, p0.y, t0), u1 = __builtin_fmaf(2.0f, p1.y, t1);
              accmin1 = fminf(fminf(accmin1, t0), t1);
              accmax1 = fmaxf(fmaxf(accmax1, u0), u1); }
            { float t0 = xm0 * p0.z, t1 = xm1 * p1.z;
              float u0 = __builtin_fmaf(2.0f, p0.z, t0), u1 = __builtin_fmaf(2.0f, p1.z, t1);
              accmin2 = fminf(fminf(accmin2, t0), t1);
              accmax2 = fmaxf(fmaxf(accmax2, u0), u1); }
            { float t0 = xm0 * p0.w, t1 = xm1 * p1.w;
              float u0 = __builtin_fmaf(2.0f, p0.w, t0), u1 = __builtin_fmaf(2.0f, p1.w, t1);
              accmin3 = fminf(fminf(accmin3, t0), t1);
              accmax3 = fmaxf(fmaxf(accmax3, u0), u1); }
        }
    }

    // ---- epilogue: node softmax + combine, coalesced float4 store ----
    const int o = o0 + to * 4;
    float4 nw0 = *reinterpret_cast<const float4*>(pnw + 2 * (size_t)o);      // o, o+1
    float4 nw1 = *reinterpret_cast<const float4*>(pnw + 2 * (size_t)o + 4);  // o+2, o+3
    float4 r;
    { float n0 = __builtin_amdgcn_rcpf(1.0f + __expf(nw0.y - nw0.x));
      r.x = (accmin0 + 1.0f) * n0 + (accmax0 - 1.0f) * (1.0f - n0); }
    { float n0 = __builtin_amdgcn_rcpf(1.0f + __expf(nw0.w - nw0.z));
      r.y = (accmin1 + 1.0f) * n0 + (accmax1 - 1.0f) * (1.0f - n0); }
    { float n0 = __builtin_amdgcn_rcpf(1.0f + __expf(nw1.y - nw1.x));
      r.z = (accmin2 + 1.0f) * n0 + (accmax2 - 1.0f) * (1.0f - n0); }
    { float n0 = __builtin_amdgcn_rcpf(1.0f + __expf(nw1.w - nw1.z));
      r.w = (accmin3 + 1.0f) * n0 + (accmax3 - 1.0f) * (1.0f - n0); }
    *reinterpret_cast<float4*>(out + (size_t)(b0 + tb) * OUT_F + o) = r;
}

extern "C" void kernel_launch(void* const* d_in, const int* in_sizes, int n_in,
                              void* d_out, int out_size, void* d_ws, size_t ws_size,
                              hipStream_t stream) {
    const float* x   = (const float*)d_in[0];
    const float* pew = (const float*)d_in[1];
    const float* pnw = (const float*)d_in[2];
    float* out = (float*)d_out;
    int B = in_sizes[0] / IN_F;            // 2048
    dim3 grid(B / BT, OUT_F / OT);         // 64 x 8 = 512 blocks (2/CU)
    den_kernel<<<grid, NTHREADS, 0, stream>>>(x, pew, pnw, out, B);
}